// Round 8
// baseline (8348.542 us; speedup 1.0000x reference)
//
#include <hip/hip_runtime.h>

// Delayed-feedback LSTM, persistent kernel: 256 WGs (1/CU), 512 threads.
// r4-r7: storage split (AGPR stash), reduction style, barrier count and phase
// scheduling all rewritten -> time pinned at 5.0-5.5 ms while FETCH fell
// 2.26->1.3 GB and VALUBusy rose 36->46%. Issue-rate accounting reconciles
// only if v_dot2_f32_f16 is ~quarter-rate. MfmaUtil has been 0.0 all along.
// THIS ROUND: do the matmuls on the matrix pipe.
//   Serial step: gates[1024] = W_hh[1024x256] @ h[256] as 64 MFMA blocks
//   (v_mfma_f32_16x16x32_f16), h REPLICATED across all 16 B-columns.
//   With permuted rows r' = unit*4 + gate (== existing orig_row), lane l of
//   block rb holds acc = (i,f,g,o) of unit rb*4+(l>>4) -> pointwise is
//   LANE-LOCAL (no shuffles, no LDS partials); col-0 lanes write h.
//   W_hh frags/wave: 64 x 16B. 32 -> AGPRs (128, pinned "+a"; MFMA reads
//   AGPR directly - no v_accvgpr_read tax), 16 -> VGPRs, 16 -> LDS (128 KB).
//   Chunk x|fb GEMM: MFMA too (N=8 timestep cols, A streamed from L2-hot ws).
//   out matvec stays dot2 (amortized 1/8). Intrinsics -> compiler handles
//   MFMA hazards. 1 barrier/step.
// Layouts: C/D col=lane&15,row=(lane>>4)*4+reg (m89-verified, dtype-indep);
// A: lane m=l&15, k=(l>>4)*8+e; B: lane k=(l>>4)*8+e, n=l&15 (m162 tr-read
// consistent). B is replication-immune; A/C errors would fail verification.

#define BATCH   256
#define TSTEPS  1024
#define IN_DIM  64
#define HID     256
#define OUT_DIM 64
#define DELAY   20
#define CH      8
#define NCH     (TSTEPS / CH)
#define NTHR    512

typedef unsigned int u32;
typedef _Float16 half2_t __attribute__((ext_vector_type(2)));
typedef _Float16 f16x8 __attribute__((ext_vector_type(8)));
typedef float    f32x4 __attribute__((ext_vector_type(4)));
typedef u32      u32x4 __attribute__((ext_vector_type(4)));

union H2U { u32 u; half2_t h; };
union H1U { unsigned short s; _Float16 h; };

__device__ __forceinline__ u32 pack2(float a, float b) {
    H2U x; x.h = half2_t{(_Float16)a, (_Float16)b}; return x.u;
}
__device__ __forceinline__ unsigned short f16bits(float a) {
    H1U x; x.h = (_Float16)a; return x.s;
}
__device__ __forceinline__ float lo16(u32 u) {
    H1U x; x.s = (unsigned short)(u & 0xffffu); return (float)x.h;
}
__device__ __forceinline__ float hi16(u32 u) {
    H1U x; x.s = (unsigned short)(u >> 16); return (float)x.h;
}
__device__ __forceinline__ float dot2(u32 w, u32 h, float acc) {
    H2U a; a.u = w; H2U b; b.u = h;
    return __builtin_amdgcn_fdot2(a.h, b.h, acc, false);
}
__device__ __forceinline__ float sigm(float x) {
    float e = __expf(-fabsf(x));
    float p = 1.f / (1.f + e);
    return x >= 0.f ? p : 1.f - p;
}
__device__ __forceinline__ float tanh_f(float x) {
    float e = __expf(-2.f * fabsf(x));
    float r = (1.f - e) / (1.f + e);
    return x >= 0.f ? r : -r;
}
__device__ __forceinline__ f32x4 mfma16(u32x4 a, u32x4 b, f32x4 c) {
    return __builtin_amdgcn_mfma_f32_16x16x32_f16(
        __builtin_bit_cast(f16x8, a), __builtin_bit_cast(f16x8, b), c, 0, 0, 0);
}

// STATIC LDS layout (bytes), total 160384 <= 163840
#define OFF_WLF   0        // uint4[16 lf][512 tid] 131072  W_hh frags ks 6,7
#define OFF_CBQ   131072   // uint2[256 u][8 tl]     16384  chunk preacts f16x4
#define OFF_RING  147456   // ushort[20][64]          2560  fb ring (f16)
#define OFF_XF    150016   // u32[8][68]              2176  staged x|fb pairs
#define OFF_HG    152192   // ushort[16][256]         8192  h history (f16)
#define SMEM_BYTES 160384

// ws layout (bytes)
#define WS_WHHF  0         // 524288: W_hh MFMA frags [64 rb][8 ks][64 lane] u32x4
#define WS_BPKF  524288    // 262144: Wx|Wfb MFMA frags [64 rb][4 ks][64 lane]
#define WS_WOUT  786432    // 32768 : packed Wout (u32)
#define WS_BSUMQ 819200    // 4096  : bias sums float4[256 units] (i,f,g,o)
#define WS_NEED  823296

// permuted row r' = u*4 + ty  ->  original row ty*256 + u  (ty: 0=i,1=f,2=g,3=o)
__device__ __forceinline__ int orig_row(int gp) {
    return (gp & 3) * 256 + (gp >> 2);
}

__global__ void prepack(const float* __restrict__ Wx,
                        const float* __restrict__ Wfb,
                        const float* __restrict__ Whh,
                        const float* __restrict__ Wout,
                        const float* __restrict__ bih,
                        const float* __restrict__ bhh,
                        uint4* __restrict__ WhhF,
                        uint4* __restrict__ BpkF,
                        u32* __restrict__ Woutpk,
                        float4* __restrict__ bsumq)
{
    int id = blockIdx.x * 256 + threadIdx.x;
    if (id < 32768) {
        // WhhF[(rb*8+ks)*64 + l]: A-frag lane l: rows rb*16+(l&15),
        // k = ks*32 + (l>>4)*8 + 0..7 (f16 pairs per dword)
        int l = id & 63, ks = (id >> 6) & 7, rb = id >> 9;
        int r = orig_row(rb * 16 + (l & 15));
        const float* w = Whh + (size_t)r * HID + ks * 32 + (l >> 4) * 8;
        uint4 v;
        v.x = pack2(w[0], w[1]); v.y = pack2(w[2], w[3]);
        v.z = pack2(w[4], w[5]); v.w = pack2(w[6], w[7]);
        WhhF[id] = v;
    } else if (id < 49152) {
        // BpkF[(rb*4+ks)*64 + l]: x|fb A-frag, K=128 (x 0..63 | fb 64..127)
        int s = id - 32768;
        int l = s & 63, ks = (s >> 6) & 3, rb = s >> 8;
        int r = orig_row(rb * 16 + (l & 15));
        int k0 = ks * 32 + (l >> 4) * 8;
        float e[8];
#pragma unroll
        for (int d = 0; d < 8; ++d) {
            int k = k0 + d;
            e[d] = (k < 64) ? Wx[(size_t)r * 64 + k] : Wfb[(size_t)r * 64 + (k - 64)];
        }
        uint4 v;
        v.x = pack2(e[0], e[1]); v.y = pack2(e[2], e[3]);
        v.z = pack2(e[4], e[5]); v.w = pack2(e[6], e[7]);
        BpkF[s] = v;
    } else if (id < 57344) {
        int s = id - 49152;                 // (w4*64+o)*4+c
        int c = s & 3, o = (s >> 2) & 63, w4 = s >> 8;
        int kp = w4 * 4 + c;
        Woutpk[s] = pack2(Wout[o * HID + 2 * kp], Wout[o * HID + 2 * kp + 1]);
    } else if (id < 57600) {
        int u = id - 57344;
        float4 bv;
        bv.x = bih[u]       + bhh[u];
        bv.y = bih[256 + u] + bhh[256 + u];
        bv.z = bih[512 + u] + bhh[512 + u];
        bv.w = bih[768 + u] + bhh[768 + u];
        bsumq[u] = bv;
    }
}

__global__ __attribute__((amdgpu_flat_work_group_size(NTHR, NTHR)))
__attribute__((amdgpu_waves_per_eu(2, 2)))
void lstm_persist(const float* __restrict__ input,
                  const uint4* __restrict__ WhhF,
                  const uint4* __restrict__ BpkF,
                  const u32* __restrict__ Woutpk,
                  const float4* __restrict__ bsumq,
                  const float* __restrict__ bout_g,
                  float* __restrict__ out)
{
    __shared__ alignas(16) unsigned char smem[SMEM_BYTES];
    uint4*          wlf   = (uint4*)(smem + OFF_WLF);
    uint2*          cbq   = (uint2*)(smem + OFF_CBQ);
    unsigned short* ring  = (unsigned short*)(smem + OFF_RING);
    u32*            xfst  = (u32*)(smem + OFF_XF);
    unsigned short* hgs   = (unsigned short*)(smem + OFF_HG);

    const int tid = threadIdx.x;
    const int b   = blockIdx.x;
    const int w   = tid >> 6;         // wave 0..7, owns blocks w*8..w*8+7
    const int l   = tid & 63;
    const int kg  = l >> 4;           // 0..3 (K-group within frag)
    const int col = l & 15;           // MFMA column (redundant for serial)

    const float* xin  = input + (size_t)b * TSTEPS * IN_DIM;
    float*       outp = out + (size_t)b * TSTEPS * OUT_DIM;
    const float bo_reg = bout_g[tid & 63];

    // ---- init: W_hh A-frags. 32 -> AGPR, 16 -> VGPR, 16 -> LDS ----
    u32x4 wa[32];   // (bb = i>>2, ks = i&3)
    u32x4 wv[16];   // (bb = i>>1, ks = 4 + (i&1))
#pragma unroll
    for (int i = 0; i < 32; ++i) {
        wa[i] = __builtin_bit_cast(u32x4, WhhF[((w * 8 + (i >> 2)) * 8 + (i & 3)) * 64 + l]);
        asm volatile("" : "+a"(wa[i]));
    }
#pragma unroll
    for (int i = 0; i < 16; ++i) {
        wv[i] = __builtin_bit_cast(u32x4, WhhF[((w * 8 + (i >> 1)) * 8 + 4 + (i & 1)) * 64 + l]);
        asm volatile("" : "+v"(wv[i]));
    }
#pragma unroll
    for (int i = 0; i < 16; ++i)
        wlf[i * 512 + tid] = WhhF[((w * 8 + (i >> 1)) * 8 + 6 + (i & 1)) * 64 + l];

    {   // zero h history (slot 15 = h_{-1})
        u32* hz = (u32*)hgs;
        hz[tid] = 0u; hz[512 + tid] = 0u; hz[1024 + tid] = 0u; hz[1536 + tid] = 0u;
    }
    __syncthreads();

    float cst[8];
#pragma unroll
    for (int j = 0; j < 8; ++j) cst[j] = 0.f;

    // out matvec for steps [tbase, tbase+8): one (t,o) per thread (dot2 path)
    auto out_chunk = [&](int tbase) {
        const int lt = tid >> 6, o = tid & 63;
        const int t = tbase + lt;
        const uint4* hrow = (const uint4*)(hgs + (t & 15) * HID);
        const uint4* wp = (const uint4*)Woutpk;
        float a = bo_reg;
        for (int w4 = 0; w4 < 32; ++w4) {
            uint4 wvv = wp[w4 * 64 + o];
            uint4 hv = hrow[w4];
            a = dot2(wvv.x, hv.x, a); a = dot2(wvv.y, hv.y, a);
            a = dot2(wvv.z, hv.z, a); a = dot2(wvv.w, hv.w, a);
        }
        outp[(size_t)t * OUT_DIM + o] = a;
        ring[(t % DELAY) * 64 + o] = f16bits(a);
    };

#pragma unroll 1
    for (int ch = 0; ch < NCH; ++ch) {
        // re-pin weight homes each chunk (zero-cost; blocks remat/sink)
#pragma unroll
        for (int i = 0; i < 32; ++i) asm volatile("" : "+a"(wa[i]));
#pragma unroll
        for (int i = 0; i < 16; ++i) asm volatile("" : "+v"(wv[i]));

        const int t0 = ch * CH;
        if (ch > 0) out_chunk(t0 - CH);
        __syncthreads();

        // ---- stage x|fb rows (8 rows x 64 u32) as f16 pairs ----
        {
            int row = tid >> 6, p = tid & 63;
            int t = t0 + row;
            u32 v;
            if (p < 32) {
                float2 x2 = *(const float2*)(xin + (size_t)t * IN_DIM + 2 * p);
                v = pack2(x2.x, x2.y);
            } else {
                int src = t - DELAY;
                if (src >= 0) {
                    int d = 2 * (p - 32);
                    int sl = src % DELAY;
                    v = (u32)ring[sl * 64 + d] | ((u32)ring[sl * 64 + d + 1] << 16);
                } else v = 0u;
            }
            xfst[row * 68 + p] = v;
        }
        __syncthreads();

        // ---- chunk preacts via MFMA: N=8 timestep columns (cols 8..15 dup) ----
        {
            const int tc = col & 7;
            const char* xb_base = (const char*)xfst + tc * 272 + kg * 16;
#pragma unroll
            for (int g = 0; g < 2; ++g) {
                f32x4 ag[4];
#pragma unroll
                for (int j = 0; j < 4; ++j) ag[j] = f32x4{0.f, 0.f, 0.f, 0.f};
#pragma unroll
                for (int ks = 0; ks < 4; ++ks) {
                    u32x4 xb = *(const u32x4*)(xb_base + ks * 64);
#pragma unroll
                    for (int j = 0; j < 4; ++j) {
                        const int bb = g * 4 + j;
                        u32x4 af = __builtin_bit_cast(u32x4,
                            BpkF[((w * 8 + bb) * 4 + ks) * 64 + l]);
                        ag[j] = mfma16(af, xb, ag[j]);
                    }
                }
#pragma unroll
                for (int j = 0; j < 4; ++j) {
                    const int U = w * 32 + (g * 4 + j) * 4 + kg;
                    float4 bs = bsumq[U];
                    if (col < 8) {
                        uint2 o;
                        o.x = pack2(ag[j][0] + bs.x, ag[j][1] + bs.y);
                        o.y = pack2(ag[j][2] + bs.z, ag[j][3] + bs.w);
                        cbq[U * 8 + col] = o;
                    }
                }
            }
        }
        __syncthreads();

        // ---- 8 serial steps: MFMA matvec, lane-local pointwise, 1 barrier ----
#pragma unroll 1
        for (int tl = 0; tl < CH; ++tl) {
            const int t = t0 + tl;
            const char* hb = (const char*)hgs + ((t - 1) & 15) * 512 + kg * 16;
#pragma unroll
            for (int g = 0; g < 2; ++g) {
                f32x4 ac[4];
#pragma unroll
                for (int j = 0; j < 4; ++j) ac[j] = f32x4{0.f, 0.f, 0.f, 0.f};
#pragma unroll
                for (int ks = 0; ks < 8; ++ks) {
                    u32x4 hf = *(const u32x4*)(hb + ks * 64);   // h replicated cols
#pragma unroll
                    for (int j = 0; j < 4; ++j) {
                        const int bb = g * 4 + j;
                        u32x4 af;
                        if (ks < 4)      af = wa[bb * 4 + ks];
                        else if (ks < 6) af = wv[bb * 2 + (ks - 4)];
                        else             af = __builtin_bit_cast(u32x4,
                                              wlf[(bb * 2 + (ks - 6)) * 512 + tid]);
                        ac[j] = mfma16(af, hf, ac[j]);
                    }
                }
                // lane-local pointwise: lane holds (i,f,g,o) of unit U
#pragma unroll
                for (int j = 0; j < 4; ++j) {
                    const int U = w * 32 + (g * 4 + j) * 4 + kg;
                    uint2 pre = cbq[U * 8 + tl];
                    float Si = ac[j][0] + lo16(pre.x);
                    float Sf = ac[j][1] + hi16(pre.x);
                    float Sg = ac[j][2] + lo16(pre.y);
                    float So = ac[j][3] + hi16(pre.y);
                    const int cj = g * 4 + j;
                    cst[cj] = sigm(Sf) * cst[cj] + sigm(Si) * tanh_f(Sg);
                    float hv = sigm(So) * tanh_f(cst[cj]);
                    if (col == 0)
                        hgs[(t & 15) * HID + U] = f16bits(hv);
                }
            }
            __syncthreads();
        }
    }
    out_chunk(TSTEPS - CH);
}

extern "C" void kernel_launch(void* const* d_in, const int* in_sizes, int n_in,
                              void* d_out, int out_size, void* d_ws, size_t ws_size,
                              hipStream_t stream)
{
    (void)in_sizes; (void)n_in; (void)out_size;
    const float* input = (const float*)d_in[0];
    const float* Wx    = (const float*)d_in[1];
    const float* Wfb   = (const float*)d_in[2];
    const float* Whh   = (const float*)d_in[3];
    const float* bih   = (const float*)d_in[4];
    const float* bhh   = (const float*)d_in[5];
    const float* Wo    = (const float*)d_in[6];
    const float* bog   = (const float*)d_in[7];
    float* out = (float*)d_out;

    if (ws_size < (size_t)WS_NEED) return;

    uint4*  WhhF   = (uint4*)((char*)d_ws + WS_WHHF);
    uint4*  BpkF   = (uint4*)((char*)d_ws + WS_BPKF);
    u32*    Woutpk = (u32*)((char*)d_ws + WS_WOUT);
    float4* bsumq  = (float4*)((char*)d_ws + WS_BSUMQ);

    prepack<<<dim3(225), dim3(256), 0, stream>>>(
        Wx, Wfb, Whh, Wo, bih, bhh, WhhF, BpkF, Woutpk, bsumq);
    lstm_persist<<<dim3(BATCH), dim3(NTHR), 0, stream>>>(
        input, WhhF, BpkF, Woutpk, bsumq, bog, out);
}